// Round 8
// baseline (652.388 us; speedup 1.0000x reference)
//
#include <hip/hip_runtime.h>
#include <hip/hip_fp16.h>
#include <cstdint>

#define N_NODES 50000
#define M_PAD   50048
#define E_EDGES 800000
#define ETOT (E_EDGES + N_NODES)
#define G_GRAPHS 512
#define FIN 300
#define K1P 320
#define HC 256
#define NHID 300
#define NOUT 512
#define NBLK 196               // ceil(N_NODES / 256)

typedef unsigned short u16;
typedef __attribute__((ext_vector_type(8))) short short8;
typedef __attribute__((ext_vector_type(4))) float f32x4;

__device__ __forceinline__ float leaky(float x){ return x > 0.f ? x : 0.2f * x; }

__device__ __forceinline__ void split2(float v, u16& h, u16& l){
    unsigned u = __float_as_uint(v);
    h = (u16)(u >> 16);
    float r = v - __uint_as_float((unsigned)h << 16);
    l = (u16)(__float_as_uint(r) >> 16);
}

__global__ void zero_i32(int* __restrict__ p, int n){
    int i = blockIdx.x * blockDim.x + threadIdx.x;
    if (i < n) p[i] = 0;
}

__global__ void zero_f32(float* __restrict__ p, int n){
    int i = blockIdx.x * blockDim.x + threadIdx.x;
    if (i < n) p[i] = 0.f;
}

__global__ void hist_kernel(const int* __restrict__ ei, int* __restrict__ counts){
    int i = blockIdx.x * blockDim.x + threadIdx.x;
    if (i >= ETOT) return;
    int d = (i < E_EDGES) ? ei[E_EDGES + i] : (i - E_EDGES);
    atomicAdd(&counts[d], 1);
}

// ---- two-level scan ---------------------------------------------------------

__global__ __launch_bounds__(256) void bsum_kernel(const int* __restrict__ counts,
                                                   int* __restrict__ bsum){
    int b = blockIdx.x, t = threadIdx.x;
    int i = b * 256 + t;
    int v = (i < N_NODES) ? counts[i] : 0;
    #pragma unroll
    for (int o = 32; o >= 1; o >>= 1) v += __shfl_xor(v, o, 64);
    __shared__ int ws[4];
    if ((t & 63) == 0) ws[t >> 6] = v;
    __syncthreads();
    if (t == 0) bsum[b] = ws[0] + ws[1] + ws[2] + ws[3];
}

__global__ __launch_bounds__(256) void bscan_kernel(const int* __restrict__ bsum,
                                                    int* __restrict__ boff,
                                                    int* __restrict__ rs){
    int t = threadIdx.x;
    int v = (t < NBLK) ? bsum[t] : 0;
    __shared__ int sd[256];
    sd[t] = v;
    __syncthreads();
    for (int off = 1; off < 256; off <<= 1){
        int u = (t >= off) ? sd[t - off] : 0;
        __syncthreads();
        sd[t] += u;
        __syncthreads();
    }
    if (t < NBLK) boff[t] = sd[t] - v;     // exclusive
    if (t == 0) rs[N_NODES] = ETOT;
}

__global__ __launch_bounds__(256) void offsets_kernel(const int* __restrict__ counts,
                                                      const int* __restrict__ boff,
                                                      int* __restrict__ rs,
                                                      int* __restrict__ cursor){
    int b = blockIdx.x, t = threadIdx.x;
    int i = b * 256 + t;
    int v = (i < N_NODES) ? counts[i] : 0;
    __shared__ int sd[256];
    sd[t] = v;
    __syncthreads();
    for (int off = 1; off < 256; off <<= 1){
        int u = (t >= off) ? sd[t - off] : 0;
        __syncthreads();
        sd[t] += u;
        __syncthreads();
    }
    if (i < N_NODES){
        int o = boff[b] + sd[t] - v;
        rs[i] = o; cursor[i] = o;
    }
}

__global__ void scatter_kernel(const int* __restrict__ ei, int* __restrict__ cursor,
                               int* __restrict__ csr_src){
    int i = blockIdx.x * blockDim.x + threadIdx.x;
    if (i >= ETOT) return;
    int s, d;
    if (i < E_EDGES){ s = ei[i]; d = ei[E_EDGES + i]; }
    else            { s = d = i - E_EDGES; }
    int pos = atomicAdd(&cursor[d], 1);
    csr_src[pos] = s;
}

// ---- conversion kernels: fp32 -> (hi, lo) bf16 pair -------------------------

__global__ void conv_x_kernel(const float* __restrict__ x, u16* __restrict__ hi,
                              u16* __restrict__ lo){
    int row = blockIdx.x, t = threadIdx.x;          // grid M_PAD, block 320
    float v = 0.f;
    if (row < N_NODES && t < FIN) v = x[(size_t)row * FIN + t];
    u16 h, l; split2(v, h, l);
    hi[(size_t)row * K1P + t] = h;
    lo[(size_t)row * K1P + t] = l;
}

__global__ void conv_w_kernel(const float* __restrict__ W, u16* __restrict__ hi,
                              u16* __restrict__ lo, int K, int Kp){
    int col = blockIdx.x, k = threadIdx.x;          // grid 256, block Kp
    float v = (k < K) ? W[(size_t)k * HC + col] : 0.f;
    u16 h, l; split2(v, h, l);
    hi[(size_t)col * Kp + k] = h;
    lo[(size_t)col * Kp + k] = l;
}

__global__ void pad_h_kernel(u16* __restrict__ hi, u16* __restrict__ lo){
    int row = N_NODES + blockIdx.x;                 // grid 48, block 256
    int t = threadIdx.x;
    hi[(size_t)row * HC + t] = 0;
    lo[(size_t)row * HC + t] = 0;
}

// ---- split-bf16 MFMA GEMM + fused attention-logit epilogue ------------------
// Writes fp16 Cf only; als/ald accumulated via atomicAdd (block col0 = one head).
__global__ __launch_bounds__(256) void gemm_mfma(const u16* __restrict__ Ahi,
                                                 const u16* __restrict__ Alo,
                                                 const u16* __restrict__ Bhi,
                                                 const u16* __restrict__ Blo,
                                                 __half* __restrict__ Cf,
                                                 const float* __restrict__ a_s,
                                                 const float* __restrict__ a_d,
                                                 float* __restrict__ als,
                                                 float* __restrict__ ald,
                                                 int Kp, int Mvalid){
    __shared__ u16 smem[24576];                     // 48 KB
    const int t    = threadIdx.x;
    const int lane = t & 63;
    const int w    = t >> 6, wr = w >> 1, wc = w & 1;
    const int fr   = lane & 15, fq = lane >> 4;
    const int col0 = blockIdx.x * 64;
    const int row0 = blockIdx.y * 128;

    const int rA0 = t >> 2, sA0 = t & 3;
    const int rA1 = rA0 + 64;
    const int rB  = t >> 2, sB = t & 3;

    auto aoff = [](int db, int hl, int row, int slot)->int{
        return (db * 2 + hl) * 4096 + row * 32 + ((slot ^ ((row >> 1) & 3)) * 8);
    };
    auto boff = [](int db, int hl, int row, int slot)->int{
        return 16384 + (db * 2 + hl) * 2048 + row * 32 + ((slot ^ ((row >> 1) & 3)) * 8);
    };

    f32x4 acc[4][2];
    #pragma unroll
    for (int m = 0; m < 4; ++m)
        #pragma unroll
        for (int n = 0; n < 2; ++n) acc[m][n] = (f32x4){0.f, 0.f, 0.f, 0.f};

    const int nt = Kp >> 5;
    int4 va0h, va1h, va0l, va1l, vbh, vbl;

    auto stage_load = [&](int kt){
        const int k0 = kt * 32;
        size_t a0 = (size_t)(row0 + rA0) * Kp + k0 + sA0 * 8;
        size_t a1 = (size_t)(row0 + rA1) * Kp + k0 + sA0 * 8;
        size_t b  = (size_t)(col0 + rB ) * Kp + k0 + sB  * 8;
        va0h = *(const int4*)(Ahi + a0); va0l = *(const int4*)(Alo + a0);
        va1h = *(const int4*)(Ahi + a1); va1l = *(const int4*)(Alo + a1);
        vbh  = *(const int4*)(Bhi + b);  vbl  = *(const int4*)(Blo + b);
    };
    auto stage_write = [&](int db){
        *(int4*)&smem[aoff(db, 0, rA0, sA0)] = va0h;
        *(int4*)&smem[aoff(db, 1, rA0, sA0)] = va0l;
        *(int4*)&smem[aoff(db, 0, rA1, sA0)] = va1h;
        *(int4*)&smem[aoff(db, 1, rA1, sA0)] = va1l;
        *(int4*)&smem[boff(db, 0, rB,  sB )] = vbh;
        *(int4*)&smem[boff(db, 1, rB,  sB )] = vbl;
    };

    stage_load(0); stage_write(0);
    __syncthreads();

    for (int kt = 0; kt < nt; ++kt){
        const int db = kt & 1;
        if (kt + 1 < nt) stage_load(kt + 1);

        short8 af[4][2], bf[2][2];
        #pragma unroll
        for (int m = 0; m < 4; ++m){
            int row = wr * 64 + m * 16 + fr;
            af[m][0] = *(const short8*)&smem[aoff(db, 0, row, fq)];
            af[m][1] = *(const short8*)&smem[aoff(db, 1, row, fq)];
        }
        #pragma unroll
        for (int n = 0; n < 2; ++n){
            int col = wc * 32 + n * 16 + fr;
            bf[n][0] = *(const short8*)&smem[boff(db, 0, col, fq)];
            bf[n][1] = *(const short8*)&smem[boff(db, 1, col, fq)];
        }
        #pragma unroll
        for (int m = 0; m < 4; ++m)
            #pragma unroll
            for (int n = 0; n < 2; ++n){
                acc[m][n] = __builtin_amdgcn_mfma_f32_16x16x32_bf16(af[m][0], bf[n][0], acc[m][n], 0, 0, 0);
                acc[m][n] = __builtin_amdgcn_mfma_f32_16x16x32_bf16(af[m][1], bf[n][0], acc[m][n], 0, 0, 0);
                acc[m][n] = __builtin_amdgcn_mfma_f32_16x16x32_bf16(af[m][0], bf[n][1], acc[m][n], 0, 0, 0);
            }

        if (kt + 1 < nt) stage_write(db ^ 1);
        __syncthreads();
    }

    // Epilogue: fp16 store + fused attention logits.
    // C/D layout: col = lane&15 (fr), row = fq*4 + reg.
    const int head = blockIdx.x;                    // col0 = head*64
    const float asv0 = a_s[col0 + wc * 32 + fr];
    const float asv1 = a_s[col0 + wc * 32 + 16 + fr];
    const float adv0 = a_d[col0 + wc * 32 + fr];
    const float adv1 = a_d[col0 + wc * 32 + 16 + fr];

    #pragma unroll
    for (int m = 0; m < 4; ++m){
        int rowb = row0 + wr * 64 + m * 16 + fq * 4;
        #pragma unroll
        for (int r = 0; r < 4; ++r){
            int row = rowb + r;
            if (row < Mvalid){
                Cf[(size_t)row * HC + col0 + wc * 32 + fr]      = __float2half(acc[m][0][r]);
                Cf[(size_t)row * HC + col0 + wc * 32 + 16 + fr] = __float2half(acc[m][1][r]);
            }
            float ps = acc[m][0][r] * asv0 + acc[m][1][r] * asv1;
            float pd = acc[m][0][r] * adv0 + acc[m][1][r] * adv1;
            #pragma unroll
            for (int o = 8; o >= 1; o >>= 1){
                ps += __shfl_xor(ps, o, 64);
                pd += __shfl_xor(pd, o, 64);
            }
            if (fr == 0 && row < Mvalid){
                atomicAdd(&als[row * 4 + head], ps);
                atomicAdd(&ald[row * 4 + head], pd);
            }
        }
    }
}

// one wave per destination node: segment softmax + weighted aggregation (v4).
// Gathers the fp16 copy htf (8 B/lane -> 8 cache lines per edge).
__global__ __launch_bounds__(256) void aggregate_kernel(const __half* __restrict__ htf,
                                                        const float* __restrict__ als,
                                                        const float* __restrict__ ald,
                                                        const int* __restrict__ rs,
                                                        const int* __restrict__ csr,
                                                        const float* __restrict__ bias,
                                                        float* __restrict__ out,
                                                        u16* __restrict__ ohi,
                                                        u16* __restrict__ olo,
                                                        int do_relu, int mode){
    int wave = threadIdx.x >> 6, lane = threadIdx.x & 63;
    int n = blockIdx.x * 4 + wave;
    if (n >= N_NODES) return;
    const int s0 = rs[n], s1 = rs[n + 1];
    const int deg = s1 - s0;
    const int hsel = lane >> 4;             // head owning cols 4l..4l+3
    const float4 adv = *(const float4*)(ald + (size_t)n * 4);
    const float ad0 = adv.x, ad1 = adv.y, ad2 = adv.z, ad3 = adv.w;

    float4 acc = {0.f, 0.f, 0.f, 0.f};
    float sm0 = 0.f, sm1 = 0.f, sm2 = 0.f, sm3 = 0.f;

    if (deg <= 64){
        const int i = s0 + lane;
        int s = 0;
        float e0 = -1e30f, e1 = -1e30f, e2 = -1e30f, e3 = -1e30f;
        if (i < s1){
            s = csr[i];
            float4 a = *(const float4*)(als + (size_t)s * 4);
            e0 = leaky(a.x + ad0); e1 = leaky(a.y + ad1);
            e2 = leaky(a.z + ad2); e3 = leaky(a.w + ad3);
        }
        float m0 = e0, m1 = e1, m2 = e2, m3 = e3;
        #pragma unroll
        for (int o = 32; o >= 1; o >>= 1){
            m0 = fmaxf(m0, __shfl_xor(m0, o, 64));
            m1 = fmaxf(m1, __shfl_xor(m1, o, 64));
            m2 = fmaxf(m2, __shfl_xor(m2, o, 64));
            m3 = fmaxf(m3, __shfl_xor(m3, o, 64));
        }
        float ex0 = 0.f, ex1 = 0.f, ex2 = 0.f, ex3 = 0.f;
        if (i < s1){
            ex0 = __expf(e0 - m0); ex1 = __expf(e1 - m1);
            ex2 = __expf(e2 - m2); ex3 = __expf(e3 - m3);
        }
        sm0 = ex0; sm1 = ex1; sm2 = ex2; sm3 = ex3;

        const int dp = (deg + 3) & ~3;
        for (int j = 0; j < dp; j += 4){
            int sj[4]; float aw[4];
            #pragma unroll
            for (int k = 0; k < 4; ++k){
                const int jj = j + k;
                sj[k] = __shfl(s, jj, 64);
                float a0 = __shfl(ex0, jj, 64);
                float a1 = __shfl(ex1, jj, 64);
                float a2 = __shfl(ex2, jj, 64);
                float a3 = __shfl(ex3, jj, 64);
                float x0 = (hsel == 0) ? a0 : a1;
                float x1 = (hsel == 2) ? a2 : a3;
                aw[k] = (hsel < 2) ? x0 : x1;
            }
            uint2 u[4];
            #pragma unroll
            for (int k = 0; k < 4; ++k)
                u[k] = *(const uint2*)(htf + (size_t)sj[k] * HC + 4 * lane);
            #pragma unroll
            for (int k = 0; k < 4; ++k){
                float2 f01 = __half22float2(*reinterpret_cast<const __half2*>(&u[k].x));
                float2 f23 = __half22float2(*reinterpret_cast<const __half2*>(&u[k].y));
                acc.x += aw[k] * f01.x; acc.y += aw[k] * f01.y;
                acc.z += aw[k] * f23.x; acc.w += aw[k] * f23.y;
            }
        }
    } else {
        float m0 = -1e30f, m1 = -1e30f, m2 = -1e30f, m3 = -1e30f;
        for (int i = s0 + lane; i < s1; i += 64){
            int s = csr[i];
            float4 a = *(const float4*)(als + (size_t)s * 4);
            m0 = fmaxf(m0, leaky(a.x + ad0)); m1 = fmaxf(m1, leaky(a.y + ad1));
            m2 = fmaxf(m2, leaky(a.z + ad2)); m3 = fmaxf(m3, leaky(a.w + ad3));
        }
        #pragma unroll
        for (int o = 32; o >= 1; o >>= 1){
            m0 = fmaxf(m0, __shfl_xor(m0, o, 64));
            m1 = fmaxf(m1, __shfl_xor(m1, o, 64));
            m2 = fmaxf(m2, __shfl_xor(m2, o, 64));
            m3 = fmaxf(m3, __shfl_xor(m3, o, 64));
        }
        for (int base = s0; base < s1; base += 64){
            const int i = base + lane;
            int s = 0;
            float ex0 = 0.f, ex1 = 0.f, ex2 = 0.f, ex3 = 0.f;
            if (i < s1){
                s = csr[i];
                float4 a = *(const float4*)(als + (size_t)s * 4);
                ex0 = __expf(leaky(a.x + ad0) - m0);
                ex1 = __expf(leaky(a.y + ad1) - m1);
                ex2 = __expf(leaky(a.z + ad2) - m2);
                ex3 = __expf(leaky(a.w + ad3) - m3);
            }
            sm0 += ex0; sm1 += ex1; sm2 += ex2; sm3 += ex3;
            const int cnt = min(64, s1 - base);
            for (int j = 0; j < cnt; ++j){
                int   sj = __shfl(s,   j, 64);
                float a0 = __shfl(ex0, j, 64);
                float a1 = __shfl(ex1, j, 64);
                float a2 = __shfl(ex2, j, 64);
                float a3 = __shfl(ex3, j, 64);
                float x0 = (hsel == 0) ? a0 : a1;
                float x1 = (hsel == 2) ? a2 : a3;
                float aw = (hsel < 2) ? x0 : x1;
                uint2 u = *(const uint2*)(htf + (size_t)sj * HC + 4 * lane);
                float2 f01 = __half22float2(*reinterpret_cast<const __half2*>(&u.x));
                float2 f23 = __half22float2(*reinterpret_cast<const __half2*>(&u.y));
                acc.x += aw * f01.x; acc.y += aw * f01.y;
                acc.z += aw * f23.x; acc.w += aw * f23.y;
            }
        }
    }

    #pragma unroll
    for (int o = 32; o >= 1; o >>= 1){
        sm0 += __shfl_xor(sm0, o, 64);
        sm1 += __shfl_xor(sm1, o, 64);
        sm2 += __shfl_xor(sm2, o, 64);
        sm3 += __shfl_xor(sm3, o, 64);
    }
    float x0 = (hsel == 0) ? sm0 : sm1;
    float x1 = (hsel == 2) ? sm2 : sm3;
    const float inv = 1.f / (((hsel < 2) ? x0 : x1) + 1e-16f);

    const float4 bv = *(const float4*)(bias + 4 * lane);
    float v0 = acc.x * inv + bv.x;
    float v1 = acc.y * inv + bv.y;
    float v2 = acc.z * inv + bv.z;
    float v3 = acc.w * inv + bv.w;
    if (do_relu){
        v0 = fmaxf(v0, 0.f); v1 = fmaxf(v1, 0.f);
        v2 = fmaxf(v2, 0.f); v3 = fmaxf(v3, 0.f);
    }
    if (mode == 0){
        *(float4*)(out + (size_t)n * HC + 4 * lane) = (float4){v0, v1, v2, v3};
    } else {
        u16 h0, l0, h1, l1, h2, l2, h3, l3;
        split2(v0, h0, l0); split2(v1, h1, l1);
        split2(v2, h2, l2); split2(v3, h3, l3);
        ushort4 h4; h4.x = h0; h4.y = h1; h4.z = h2; h4.w = h3;
        ushort4 l4; l4.x = l0; l4.y = l1; l4.z = l2; l4.w = l3;
        size_t base = (size_t)n * HC + 4 * lane;
        *(ushort4*)(ohi + base) = h4;
        *(ushort4*)(olo + base) = l4;
    }
}

__global__ void gstart_kernel(const int* __restrict__ batch, int* __restrict__ gstart){
    int g = blockIdx.x * blockDim.x + threadIdx.x;
    if (g > G_GRAPHS) return;
    int lo = 0, hi = N_NODES;
    while (lo < hi){
        int mid = (lo + hi) >> 1;
        if (batch[mid] < g) lo = mid + 1; else hi = mid;
    }
    gstart[g] = lo;
}

__global__ __launch_bounds__(256) void pool_kernel(const float* __restrict__ h,
                                                   const int* __restrict__ gstart,
                                                   float* __restrict__ pooled){
    int g = blockIdx.x, t = threadIdx.x;
    int s0 = gstart[g], s1 = gstart[g + 1];
    float sum = 0.f;
    for (int n = s0; n < s1; ++n) sum += h[(size_t)n * HC + t];
    pooled[g * HC + t] = sum / fmaxf((float)(s1 - s0), 1.f);
}

__global__ void mlp1_kernel(const float* __restrict__ pooled, const float* __restrict__ Wm1,
                            const float* __restrict__ bm1, float* __restrict__ z){
    int g = blockIdx.x, j = threadIdx.x;
    if (j >= NHID) return;
    float acc = bm1[j];
    for (int k = 0; k < HC; ++k) acc += pooled[g * HC + k] * Wm1[(size_t)k * NHID + j];
    z[g * NHID + j] = fmaxf(acc, 0.f);
}

__global__ void mlp2_kernel(const float* __restrict__ z, const float* __restrict__ Wm2,
                            const float* __restrict__ bm2, float* __restrict__ out){
    int g = blockIdx.x, j = threadIdx.x;
    float acc = bm2[j];
    for (int k = 0; k < NHID; ++k) acc += z[g * NHID + k] * Wm2[(size_t)k * NOUT + j];
    out[g * NOUT + j] = acc;
}

extern "C" void kernel_launch(void* const* d_in, const int* in_sizes, int n_in,
                              void* d_out, int out_size, void* d_ws, size_t ws_size,
                              hipStream_t stream){
    const float* x    = (const float*)d_in[0];
    const int*   ei   = (const int*)  d_in[1];
    const int*   batch= (const int*)  d_in[2];
    const float* W1   = (const float*)d_in[3];
    const float* a1s  = (const float*)d_in[4];
    const float* a1d  = (const float*)d_in[5];
    const float* b1   = (const float*)d_in[6];
    const float* W2   = (const float*)d_in[7];
    const float* a2s  = (const float*)d_in[8];
    const float* a2d  = (const float*)d_in[9];
    const float* b2   = (const float*)d_in[10];
    const float* W3   = (const float*)d_in[11];
    const float* a3s  = (const float*)d_in[12];
    const float* a3d  = (const float*)d_in[13];
    const float* b3   = (const float*)d_in[14];
    const float* Wm1  = (const float*)d_in[15];
    const float* bm1  = (const float*)d_in[16];
    const float* Wm2  = (const float*)d_in[17];
    const float* bm2  = (const float*)d_in[18];
    float* out = (float*)d_out;

    char* ws = (char*)d_ws;
    size_t off = 0;
    auto alloc = [&](size_t bytes)->char*{
        char* p = ws + off;
        off = (off + bytes + 255) & ~(size_t)255;
        return p;
    };
    u16*   xhi    = (u16*)  alloc((size_t)M_PAD * K1P * 2);
    u16*   xlo    = (u16*)  alloc((size_t)M_PAD * K1P * 2);
    float* hbuf   = (float*)xhi;   // aliased: xhi/xlo dead after layer-1 GEMM (64 MB region)
    u16*   hhi    = (u16*)  alloc((size_t)M_PAD * HC * 2);
    u16*   hlo    = (u16*)  alloc((size_t)M_PAD * HC * 2);
    __half* htf   = (__half*)alloc((size_t)N_NODES * HC * 2);
    u16*   wt1h   = (u16*)  alloc((size_t)HC * K1P * 2);
    u16*   wt1l   = (u16*)  alloc((size_t)HC * K1P * 2);
    u16*   wt2h   = (u16*)  alloc((size_t)HC * HC * 2);
    u16*   wt2l   = (u16*)  alloc((size_t)HC * HC * 2);
    u16*   wt3h   = (u16*)  alloc((size_t)HC * HC * 2);
    u16*   wt3l   = (u16*)  alloc((size_t)HC * HC * 2);
    float* als    = (float*)alloc((size_t)N_NODES * 4 * 4);   // contiguous with ald
    float* ald    = (float*)alloc((size_t)N_NODES * 4 * 4);
    int*   counts = (int*)  alloc((size_t)N_NODES * 4);
    int*   rs     = (int*)  alloc((size_t)(N_NODES + 1) * 4);
    int*   cursor = (int*)  alloc((size_t)N_NODES * 4);
    int*   csr    = (int*)  alloc((size_t)ETOT * 4);
    int*   bsum   = (int*)  alloc(256 * 4);
    int*   boffs  = (int*)  alloc(256 * 4);
    int*   gstart = (int*)  alloc((size_t)(G_GRAPHS + 1) * 4);
    float* pooled = (float*)alloc((size_t)G_GRAPHS * HC * 4);
    float* zbuf   = (float*)alloc((size_t)G_GRAPHS * NHID * 4);

    conv_x_kernel<<<M_PAD, K1P, 0, stream>>>(x, xhi, xlo);
    conv_w_kernel<<<HC, K1P, 0, stream>>>(W1, wt1h, wt1l, FIN, K1P);
    conv_w_kernel<<<HC, HC, 0, stream>>>(W2, wt2h, wt2l, HC, HC);
    conv_w_kernel<<<HC, HC, 0, stream>>>(W3, wt3h, wt3l, HC, HC);
    pad_h_kernel<<<M_PAD - N_NODES, HC, 0, stream>>>(hhi, hlo);

    zero_i32<<<(N_NODES + 255) / 256, 256, 0, stream>>>(counts, N_NODES);
    hist_kernel<<<(ETOT + 255) / 256, 256, 0, stream>>>(ei, counts);
    bsum_kernel<<<NBLK, 256, 0, stream>>>(counts, bsum);
    bscan_kernel<<<1, 256, 0, stream>>>(bsum, boffs, rs);
    offsets_kernel<<<NBLK, 256, 0, stream>>>(counts, boffs, rs, cursor);
    scatter_kernel<<<(ETOT + 255) / 256, 256, 0, stream>>>(ei, cursor, csr);
    gstart_kernel<<<3, 256, 0, stream>>>(batch, gstart);

    dim3 ggrid(4, M_PAD / 128);
    const int ZN = N_NODES * 4 * 2;        // als + ald (contiguous)

    // layer 1
    zero_f32<<<(ZN + 255) / 256, 256, 0, stream>>>(als, ZN);
    gemm_mfma<<<ggrid, 256, 0, stream>>>(xhi, xlo, wt1h, wt1l, htf, a1s, a1d,
                                         als, ald, K1P, N_NODES);
    aggregate_kernel<<<(N_NODES + 3) / 4, 256, 0, stream>>>(htf, als, ald, rs, csr,
                                                            b1, hbuf, hhi, hlo, 1, 1);
    // layer 2
    zero_f32<<<(ZN + 255) / 256, 256, 0, stream>>>(als, ZN);
    gemm_mfma<<<ggrid, 256, 0, stream>>>(hhi, hlo, wt2h, wt2l, htf, a2s, a2d,
                                         als, ald, HC, N_NODES);
    aggregate_kernel<<<(N_NODES + 3) / 4, 256, 0, stream>>>(htf, als, ald, rs, csr,
                                                            b2, hbuf, hhi, hlo, 1, 1);
    // layer 3
    zero_f32<<<(ZN + 255) / 256, 256, 0, stream>>>(als, ZN);
    gemm_mfma<<<ggrid, 256, 0, stream>>>(hhi, hlo, wt3h, wt3l, htf, a3s, a3d,
                                         als, ald, HC, N_NODES);
    aggregate_kernel<<<(N_NODES + 3) / 4, 256, 0, stream>>>(htf, als, ald, rs, csr,
                                                            b3, hbuf, hhi, hlo, 0, 0);

    pool_kernel<<<G_GRAPHS, 256, 0, stream>>>(hbuf, gstart, pooled);
    mlp1_kernel<<<G_GRAPHS, 320, 0, stream>>>(pooled, Wm1, bm1, zbuf);
    mlp2_kernel<<<G_GRAPHS, 512, 0, stream>>>(zbuf, Wm2, bm2, out);
}

// Round 9
// 527.887 us; speedup vs baseline: 1.2358x; 1.2358x over previous
//
#include <hip/hip_runtime.h>
#include <hip/hip_fp16.h>
#include <cstdint>

#define N_NODES 50000
#define M_PAD   50048
#define E_EDGES 800000
#define ETOT (E_EDGES + N_NODES)
#define G_GRAPHS 512
#define FIN 300
#define K1P 320
#define HC 256
#define NHID 300
#define NOUT 512
#define NBLK 196               // ceil(N_NODES / 256)

typedef unsigned short u16;
typedef __attribute__((ext_vector_type(8))) _Float16 f16x8;
typedef __attribute__((ext_vector_type(4))) float f32x4;

__device__ __forceinline__ float leaky(float x){ return x > 0.f ? x : 0.2f * x; }

__global__ void zero_i32(int* __restrict__ p, int n){
    int i = blockIdx.x * blockDim.x + threadIdx.x;
    if (i < n) p[i] = 0;
}

__global__ void hist_kernel(const int* __restrict__ ei, int* __restrict__ counts){
    int i = blockIdx.x * blockDim.x + threadIdx.x;
    if (i >= ETOT) return;
    int d = (i < E_EDGES) ? ei[E_EDGES + i] : (i - E_EDGES);
    atomicAdd(&counts[d], 1);
}

// ---- two-level scan ---------------------------------------------------------

__global__ __launch_bounds__(256) void bsum_kernel(const int* __restrict__ counts,
                                                   int* __restrict__ bsum){
    int b = blockIdx.x, t = threadIdx.x;
    int i = b * 256 + t;
    int v = (i < N_NODES) ? counts[i] : 0;
    #pragma unroll
    for (int o = 32; o >= 1; o >>= 1) v += __shfl_xor(v, o, 64);
    __shared__ int ws[4];
    if ((t & 63) == 0) ws[t >> 6] = v;
    __syncthreads();
    if (t == 0) bsum[b] = ws[0] + ws[1] + ws[2] + ws[3];
}

__global__ __launch_bounds__(256) void bscan_kernel(const int* __restrict__ bsum,
                                                    int* __restrict__ boff,
                                                    int* __restrict__ rs){
    int t = threadIdx.x;
    int v = (t < NBLK) ? bsum[t] : 0;
    __shared__ int sd[256];
    sd[t] = v;
    __syncthreads();
    for (int off = 1; off < 256; off <<= 1){
        int u = (t >= off) ? sd[t - off] : 0;
        __syncthreads();
        sd[t] += u;
        __syncthreads();
    }
    if (t < NBLK) boff[t] = sd[t] - v;     // exclusive
    if (t == 0) rs[N_NODES] = ETOT;
}

__global__ __launch_bounds__(256) void offsets_kernel(const int* __restrict__ counts,
                                                      const int* __restrict__ boff,
                                                      int* __restrict__ rs,
                                                      int* __restrict__ cursor){
    int b = blockIdx.x, t = threadIdx.x;
    int i = b * 256 + t;
    int v = (i < N_NODES) ? counts[i] : 0;
    __shared__ int sd[256];
    sd[t] = v;
    __syncthreads();
    for (int off = 1; off < 256; off <<= 1){
        int u = (t >= off) ? sd[t - off] : 0;
        __syncthreads();
        sd[t] += u;
        __syncthreads();
    }
    if (i < N_NODES){
        int o = boff[b] + sd[t] - v;
        rs[i] = o; cursor[i] = o;
    }
}

__global__ void scatter_kernel(const int* __restrict__ ei, int* __restrict__ cursor,
                               int* __restrict__ csr_src){
    int i = blockIdx.x * blockDim.x + threadIdx.x;
    if (i >= ETOT) return;
    int s, d;
    if (i < E_EDGES){ s = ei[i]; d = ei[E_EDGES + i]; }
    else            { s = d = i - E_EDGES; }
    int pos = atomicAdd(&cursor[d], 1);
    csr_src[pos] = s;
}

// ---- conversion kernels: fp32 -> fp16 ---------------------------------------

__global__ void conv_x_kernel(const float* __restrict__ x, __half* __restrict__ xf){
    int row = blockIdx.x, t = threadIdx.x;          // grid M_PAD, block 320
    float v = 0.f;
    if (row < N_NODES && t < FIN) v = x[(size_t)row * FIN + t];
    xf[(size_t)row * K1P + t] = __float2half(v);
}

__global__ void conv_w_kernel(const float* __restrict__ W, __half* __restrict__ wf,
                              int K, int Kp){
    int col = blockIdx.x, k = threadIdx.x;          // grid 256, block Kp
    float v = (k < K) ? W[(size_t)k * HC + col] : 0.f;
    wf[(size_t)col * Kp + k] = __float2half(v);
}

__global__ void pad_h_kernel(__half* __restrict__ hf){
    int row = N_NODES + blockIdx.x;                 // grid 48, block 256
    int t = threadIdx.x;
    hf[(size_t)row * HC + t] = __float2half(0.f);
}

// ---- fp16 MFMA GEMM: Cf[M,256] = A @ W (fp32 accumulate) --------------------
// A fp16 [M_PAD][Kp], Bt fp16 [256][Kp]; tile 128x64, BK=32, 4 waves, dbuf LDS.
__global__ __launch_bounds__(256) void gemm_fp16(const __half* __restrict__ A,
                                                 const __half* __restrict__ Bt,
                                                 __half* __restrict__ Cf,
                                                 int Kp, int Mvalid){
    __shared__ u16 smem[12288];                     // 24 KB
    const int t    = threadIdx.x;
    const int lane = t & 63;
    const int w    = t >> 6, wr = w >> 1, wc = w & 1;
    const int fr   = lane & 15, fq = lane >> 4;
    const int col0 = blockIdx.x * 64;
    const int row0 = blockIdx.y * 128;

    const int rA0 = t >> 2, sA0 = t & 3;            // A rows 0..63
    const int rA1 = rA0 + 64;                       // A rows 64..127
    const int rB  = t >> 2, sB = t & 3;             // B rows 0..63

    // XOR swizzle keeps b128 frag reads conflict-free
    auto aoff = [](int db, int row, int slot)->int{
        return db * 4096 + row * 32 + ((slot ^ ((row >> 1) & 3)) * 8);
    };
    auto boff = [](int db, int row, int slot)->int{
        return 8192 + db * 2048 + row * 32 + ((slot ^ ((row >> 1) & 3)) * 8);
    };

    f32x4 acc[4][2];
    #pragma unroll
    for (int m = 0; m < 4; ++m)
        #pragma unroll
        for (int n = 0; n < 2; ++n) acc[m][n] = (f32x4){0.f, 0.f, 0.f, 0.f};

    const int nt = Kp >> 5;
    int4 va0, va1, vb;

    auto stage_load = [&](int kt){
        const int k0 = kt * 32;
        va0 = *(const int4*)(A  + (size_t)(row0 + rA0) * Kp + k0 + sA0 * 8);
        va1 = *(const int4*)(A  + (size_t)(row0 + rA1) * Kp + k0 + sA0 * 8);
        vb  = *(const int4*)(Bt + (size_t)(col0 + rB ) * Kp + k0 + sB  * 8);
    };
    auto stage_write = [&](int db){
        *(int4*)&smem[aoff(db, rA0, sA0)] = va0;
        *(int4*)&smem[aoff(db, rA1, sA0)] = va1;
        *(int4*)&smem[boff(db, rB,  sB )] = vb;
    };

    stage_load(0); stage_write(0);
    __syncthreads();

    for (int kt = 0; kt < nt; ++kt){
        const int db = kt & 1;
        if (kt + 1 < nt) stage_load(kt + 1);        // issue early

        f16x8 af[4], bf[2];
        #pragma unroll
        for (int m = 0; m < 4; ++m){
            int row = wr * 64 + m * 16 + fr;
            af[m] = *(const f16x8*)&smem[aoff(db, row, fq)];
        }
        #pragma unroll
        for (int n = 0; n < 2; ++n){
            int col = wc * 32 + n * 16 + fr;
            bf[n] = *(const f16x8*)&smem[boff(db, col, fq)];
        }
        #pragma unroll
        for (int m = 0; m < 4; ++m)
            #pragma unroll
            for (int n = 0; n < 2; ++n)
                acc[m][n] = __builtin_amdgcn_mfma_f32_16x16x32_f16(af[m], bf[n], acc[m][n], 0, 0, 0);

        if (kt + 1 < nt) stage_write(db ^ 1);       // write late
        __syncthreads();
    }

    // C/D layout: col = lane&15, row = (lane>>4)*4 + reg
    #pragma unroll
    for (int m = 0; m < 4; ++m){
        int row = row0 + wr * 64 + m * 16 + fq * 4;
        #pragma unroll
        for (int n = 0; n < 2; ++n){
            int col = col0 + wc * 32 + n * 16 + fr;
            #pragma unroll
            for (int r = 0; r < 4; ++r){
                if (row + r < Mvalid)
                    Cf[(size_t)(row + r) * HC + col] = __float2half(acc[m][n][r]);
            }
        }
    }
}

// per-node attention logits from fp16 htf (lane -> cols 4l..4l+3)
__global__ __launch_bounds__(256) void al_kernel(const __half* __restrict__ htf,
                                                 const float* __restrict__ a_s,
                                                 const float* __restrict__ a_d,
                                                 float* __restrict__ als,
                                                 float* __restrict__ ald){
    int wave = threadIdx.x >> 6, lane = threadIdx.x & 63;
    int n = blockIdx.x * 4 + wave;
    if (n >= N_NODES) return;
    const uint2 u = *(const uint2*)(htf + (size_t)n * HC + 4 * lane);
    float2 f01 = __half22float2(*reinterpret_cast<const __half2*>(&u.x));
    float2 f23 = __half22float2(*reinterpret_cast<const __half2*>(&u.y));
    const float4 as4 = *(const float4*)(a_s + 4 * lane);
    const float4 ad4 = *(const float4*)(a_d + 4 * lane);
    float ps = f01.x * as4.x + f01.y * as4.y + f23.x * as4.z + f23.y * as4.w;
    float pd = f01.x * ad4.x + f01.y * ad4.y + f23.x * ad4.z + f23.y * ad4.w;
    #pragma unroll
    for (int o = 8; o >= 1; o >>= 1){       // reduce within 16-lane head group
        ps += __shfl_xor(ps, o, 64);
        pd += __shfl_xor(pd, o, 64);
    }
    if ((lane & 15) == 0){
        als[n * 4 + (lane >> 4)] = ps;
        ald[n * 4 + (lane >> 4)] = pd;
    }
}

// one wave per destination node: segment softmax + weighted aggregation.
// mode 0: fp32 out; mode 1: fp16 hf out.
__global__ __launch_bounds__(256) void aggregate_kernel(const __half* __restrict__ htf,
                                                        const float* __restrict__ als,
                                                        const float* __restrict__ ald,
                                                        const int* __restrict__ rs,
                                                        const int* __restrict__ csr,
                                                        const float* __restrict__ bias,
                                                        float* __restrict__ out,
                                                        __half* __restrict__ hf,
                                                        int do_relu, int mode){
    int wave = threadIdx.x >> 6, lane = threadIdx.x & 63;
    int n = blockIdx.x * 4 + wave;
    if (n >= N_NODES) return;
    const int s0 = rs[n], s1 = rs[n + 1];
    const int deg = s1 - s0;
    const int hsel = lane >> 4;             // head owning cols 4l..4l+3
    const float4 adv = *(const float4*)(ald + (size_t)n * 4);
    const float ad0 = adv.x, ad1 = adv.y, ad2 = adv.z, ad3 = adv.w;

    float4 acc = {0.f, 0.f, 0.f, 0.f};
    float sm0 = 0.f, sm1 = 0.f, sm2 = 0.f, sm3 = 0.f;

    if (deg <= 64){
        const int i = s0 + lane;
        int s = 0;
        float e0 = -1e30f, e1 = -1e30f, e2 = -1e30f, e3 = -1e30f;
        if (i < s1){
            s = csr[i];
            float4 a = *(const float4*)(als + (size_t)s * 4);
            e0 = leaky(a.x + ad0); e1 = leaky(a.y + ad1);
            e2 = leaky(a.z + ad2); e3 = leaky(a.w + ad3);
        }
        float m0 = e0, m1 = e1, m2 = e2, m3 = e3;
        #pragma unroll
        for (int o = 32; o >= 1; o >>= 1){
            m0 = fmaxf(m0, __shfl_xor(m0, o, 64));
            m1 = fmaxf(m1, __shfl_xor(m1, o, 64));
            m2 = fmaxf(m2, __shfl_xor(m2, o, 64));
            m3 = fmaxf(m3, __shfl_xor(m3, o, 64));
        }
        float ex0 = 0.f, ex1 = 0.f, ex2 = 0.f, ex3 = 0.f;
        if (i < s1){
            ex0 = __expf(e0 - m0); ex1 = __expf(e1 - m1);
            ex2 = __expf(e2 - m2); ex3 = __expf(e3 - m3);
        }
        sm0 = ex0; sm1 = ex1; sm2 = ex2; sm3 = ex3;

        const int dp = (deg + 3) & ~3;
        for (int j = 0; j < dp; j += 4){
            int sj[4]; float aw[4];
            #pragma unroll
            for (int k = 0; k < 4; ++k){
                const int jj = j + k;
                sj[k] = __shfl(s, jj, 64);
                float a0 = __shfl(ex0, jj, 64);
                float a1 = __shfl(ex1, jj, 64);
                float a2 = __shfl(ex2, jj, 64);
                float a3 = __shfl(ex3, jj, 64);
                float x0 = (hsel == 0) ? a0 : a1;
                float x1 = (hsel == 2) ? a2 : a3;
                aw[k] = (hsel < 2) ? x0 : x1;
            }
            uint2 u[4];
            #pragma unroll
            for (int k = 0; k < 4; ++k)
                u[k] = *(const uint2*)(htf + (size_t)sj[k] * HC + 4 * lane);
            #pragma unroll
            for (int k = 0; k < 4; ++k){
                float2 f01 = __half22float2(*reinterpret_cast<const __half2*>(&u[k].x));
                float2 f23 = __half22float2(*reinterpret_cast<const __half2*>(&u[k].y));
                acc.x += aw[k] * f01.x; acc.y += aw[k] * f01.y;
                acc.z += aw[k] * f23.x; acc.w += aw[k] * f23.y;
            }
        }
    } else {
        float m0 = -1e30f, m1 = -1e30f, m2 = -1e30f, m3 = -1e30f;
        for (int i = s0 + lane; i < s1; i += 64){
            int s = csr[i];
            float4 a = *(const float4*)(als + (size_t)s * 4);
            m0 = fmaxf(m0, leaky(a.x + ad0)); m1 = fmaxf(m1, leaky(a.y + ad1));
            m2 = fmaxf(m2, leaky(a.z + ad2)); m3 = fmaxf(m3, leaky(a.w + ad3));
        }
        #pragma unroll
        for (int o = 32; o >= 1; o >>= 1){
            m0 = fmaxf(m0, __shfl_xor(m0, o, 64));
            m1 = fmaxf(m1, __shfl_xor(m1, o, 64));
            m2 = fmaxf(m2, __shfl_xor(m2, o, 64));
            m3 = fmaxf(m3, __shfl_xor(m3, o, 64));
        }
        for (int base = s0; base < s1; base += 64){
            const int i = base + lane;
            int s = 0;
            float ex0 = 0.f, ex1 = 0.f, ex2 = 0.f, ex3 = 0.f;
            if (i < s1){
                s = csr[i];
                float4 a = *(const float4*)(als + (size_t)s * 4);
                ex0 = __expf(leaky(a.x + ad0) - m0);
                ex1 = __expf(leaky(a.y + ad1) - m1);
                ex2 = __expf(leaky(a.z + ad2) - m2);
                ex3 = __expf(leaky(a.w + ad3) - m3);
            }
            sm0 += ex0; sm1 += ex1; sm2 += ex2; sm3 += ex3;
            const int cnt = min(64, s1 - base);
            for (int j = 0; j < cnt; ++j){
                int   sj = __shfl(s,   j, 64);
                float a0 = __shfl(ex0, j, 64);
                float a1 = __shfl(ex1, j, 64);
                float a2 = __shfl(ex2, j, 64);
                float a3 = __shfl(ex3, j, 64);
                float x0 = (hsel == 0) ? a0 : a1;
                float x1 = (hsel == 2) ? a2 : a3;
                float aw = (hsel < 2) ? x0 : x1;
                uint2 u = *(const uint2*)(htf + (size_t)sj * HC + 4 * lane);
                float2 f01 = __half22float2(*reinterpret_cast<const __half2*>(&u.x));
                float2 f23 = __half22float2(*reinterpret_cast<const __half2*>(&u.y));
                acc.x += aw * f01.x; acc.y += aw * f01.y;
                acc.z += aw * f23.x; acc.w += aw * f23.y;
            }
        }
    }

    #pragma unroll
    for (int o = 32; o >= 1; o >>= 1){
        sm0 += __shfl_xor(sm0, o, 64);
        sm1 += __shfl_xor(sm1, o, 64);
        sm2 += __shfl_xor(sm2, o, 64);
        sm3 += __shfl_xor(sm3, o, 64);
    }
    float x0 = (hsel == 0) ? sm0 : sm1;
    float x1 = (hsel == 2) ? sm2 : sm3;
    const float inv = 1.f / (((hsel < 2) ? x0 : x1) + 1e-16f);

    const float4 bv = *(const float4*)(bias + 4 * lane);
    float v0 = acc.x * inv + bv.x;
    float v1 = acc.y * inv + bv.y;
    float v2 = acc.z * inv + bv.z;
    float v3 = acc.w * inv + bv.w;
    if (do_relu){
        v0 = fmaxf(v0, 0.f); v1 = fmaxf(v1, 0.f);
        v2 = fmaxf(v2, 0.f); v3 = fmaxf(v3, 0.f);
    }
    if (mode == 0){
        *(float4*)(out + (size_t)n * HC + 4 * lane) = (float4){v0, v1, v2, v3};
    } else {
        ushort4 p;
        p.x = __half_as_ushort(__float2half(v0));
        p.y = __half_as_ushort(__float2half(v1));
        p.z = __half_as_ushort(__float2half(v2));
        p.w = __half_as_ushort(__float2half(v3));
        *(ushort4*)((u16*)hf + (size_t)n * HC + 4 * lane) = p;
    }
}

__global__ void gstart_kernel(const int* __restrict__ batch, int* __restrict__ gstart){
    int g = blockIdx.x * blockDim.x + threadIdx.x;
    if (g > G_GRAPHS) return;
    int lo = 0, hi = N_NODES;
    while (lo < hi){
        int mid = (lo + hi) >> 1;
        if (batch[mid] < g) lo = mid + 1; else hi = mid;
    }
    gstart[g] = lo;
}

__global__ __launch_bounds__(256) void pool_kernel(const float* __restrict__ h,
                                                   const int* __restrict__ gstart,
                                                   float* __restrict__ pooled){
    int g = blockIdx.x, t = threadIdx.x;
    int s0 = gstart[g], s1 = gstart[g + 1];
    float sum = 0.f;
    for (int n = s0; n < s1; ++n) sum += h[(size_t)n * HC + t];
    pooled[g * HC + t] = sum / fmaxf((float)(s1 - s0), 1.f);
}

__global__ void mlp1_kernel(const float* __restrict__ pooled, const float* __restrict__ Wm1,
                            const float* __restrict__ bm1, float* __restrict__ z){
    int g = blockIdx.x, j = threadIdx.x;
    if (j >= NHID) return;
    float acc = bm1[j];
    for (int k = 0; k < HC; ++k) acc += pooled[g * HC + k] * Wm1[(size_t)k * NHID + j];
    z[g * NHID + j] = fmaxf(acc, 0.f);
}

__global__ void mlp2_kernel(const float* __restrict__ z, const float* __restrict__ Wm2,
                            const float* __restrict__ bm2, float* __restrict__ out){
    int g = blockIdx.x, j = threadIdx.x;
    float acc = bm2[j];
    for (int k = 0; k < NHID; ++k) acc += z[g * NHID + k] * Wm2[(size_t)k * NOUT + j];
    out[g * NOUT + j] = acc;
}

extern "C" void kernel_launch(void* const* d_in, const int* in_sizes, int n_in,
                              void* d_out, int out_size, void* d_ws, size_t ws_size,
                              hipStream_t stream){
    const float* x    = (const float*)d_in[0];
    const int*   ei   = (const int*)  d_in[1];
    const int*   batch= (const int*)  d_in[2];
    const float* W1   = (const float*)d_in[3];
    const float* a1s  = (const float*)d_in[4];
    const float* a1d  = (const float*)d_in[5];
    const float* b1   = (const float*)d_in[6];
    const float* W2   = (const float*)d_in[7];
    const float* a2s  = (const float*)d_in[8];
    const float* a2d  = (const float*)d_in[9];
    const float* b2   = (const float*)d_in[10];
    const float* W3   = (const float*)d_in[11];
    const float* a3s  = (const float*)d_in[12];
    const float* a3d  = (const float*)d_in[13];
    const float* b3   = (const float*)d_in[14];
    const float* Wm1  = (const float*)d_in[15];
    const float* bm1  = (const float*)d_in[16];
    const float* Wm2  = (const float*)d_in[17];
    const float* bm2  = (const float*)d_in[18];
    float* out = (float*)d_out;

    char* ws = (char*)d_ws;
    size_t off = 0;
    auto alloc = [&](size_t bytes)->char*{
        char* p = ws + off;
        off = (off + bytes + 255) & ~(size_t)255;
        return p;
    };
    __half* xf    = (__half*)alloc((size_t)M_PAD * K1P * 2);    // 32 MB
    __half* hf    = (__half*)alloc((size_t)M_PAD * HC * 2);     // 25.6 MB
    __half* htf   = (__half*)alloc((size_t)N_NODES * HC * 2);   // 25.6 MB
    float* hbuf   = (float*)alloc((size_t)N_NODES * HC * 4);    // 51 MB
    __half* wt1   = (__half*)alloc((size_t)HC * K1P * 2);
    __half* wt2   = (__half*)alloc((size_t)HC * HC * 2);
    __half* wt3   = (__half*)alloc((size_t)HC * HC * 2);
    float* als    = (float*)alloc((size_t)N_NODES * 4 * 4);
    float* ald    = (float*)alloc((size_t)N_NODES * 4 * 4);
    int*   counts = (int*)  alloc((size_t)N_NODES * 4);
    int*   rs     = (int*)  alloc((size_t)(N_NODES + 1) * 4);
    int*   cursor = (int*)  alloc((size_t)N_NODES * 4);
    int*   csr    = (int*)  alloc((size_t)ETOT * 4);
    int*   bsum   = (int*)  alloc(256 * 4);
    int*   boffs  = (int*)  alloc(256 * 4);
    int*   gstart = (int*)  alloc((size_t)(G_GRAPHS + 1) * 4);
    float* pooled = (float*)alloc((size_t)G_GRAPHS * HC * 4);
    float* zbuf   = (float*)alloc((size_t)G_GRAPHS * NHID * 4);

    conv_x_kernel<<<M_PAD, K1P, 0, stream>>>(x, xf);
    conv_w_kernel<<<HC, K1P, 0, stream>>>(W1, wt1, FIN, K1P);
    conv_w_kernel<<<HC, HC, 0, stream>>>(W2, wt2, HC, HC);
    conv_w_kernel<<<HC, HC, 0, stream>>>(W3, wt3, HC, HC);
    pad_h_kernel<<<M_PAD - N_NODES, HC, 0, stream>>>(hf);

    zero_i32<<<(N_NODES + 255) / 256, 256, 0, stream>>>(counts, N_NODES);
    hist_kernel<<<(ETOT + 255) / 256, 256, 0, stream>>>(ei, counts);
    bsum_kernel<<<NBLK, 256, 0, stream>>>(counts, bsum);
    bscan_kernel<<<1, 256, 0, stream>>>(bsum, boffs, rs);
    offsets_kernel<<<NBLK, 256, 0, stream>>>(counts, boffs, rs, cursor);
    scatter_kernel<<<(ETOT + 255) / 256, 256, 0, stream>>>(ei, cursor, csr);
    gstart_kernel<<<3, 256, 0, stream>>>(batch, gstart);

    dim3 ggrid(4, M_PAD / 128);

    // layer 1
    gemm_fp16<<<ggrid, 256, 0, stream>>>(xf, wt1, htf, K1P, N_NODES);
    al_kernel<<<(N_NODES + 3) / 4, 256, 0, stream>>>(htf, a1s, a1d, als, ald);
    aggregate_kernel<<<(N_NODES + 3) / 4, 256, 0, stream>>>(htf, als, ald, rs, csr,
                                                            b1, hbuf, hf, 1, 1);
    // layer 2
    gemm_fp16<<<ggrid, 256, 0, stream>>>(hf, wt2, htf, HC, N_NODES);
    al_kernel<<<(N_NODES + 3) / 4, 256, 0, stream>>>(htf, a2s, a2d, als, ald);
    aggregate_kernel<<<(N_NODES + 3) / 4, 256, 0, stream>>>(htf, als, ald, rs, csr,
                                                            b2, hbuf, hf, 1, 1);
    // layer 3
    gemm_fp16<<<ggrid, 256, 0, stream>>>(hf, wt3, htf, HC, N_NODES);
    al_kernel<<<(N_NODES + 3) / 4, 256, 0, stream>>>(htf, a3s, a3d, als, ald);
    aggregate_kernel<<<(N_NODES + 3) / 4, 256, 0, stream>>>(htf, als, ald, rs, csr,
                                                            b3, hbuf, hf, 0, 0);

    pool_kernel<<<G_GRAPHS, 256, 0, stream>>>(hbuf, gstart, pooled);
    mlp1_kernel<<<G_GRAPHS, 320, 0, stream>>>(pooled, Wm1, bm1, zbuf);
    mlp2_kernel<<<G_GRAPHS, 512, 0, stream>>>(zbuf, Wm2, bm2, out);
}

// Round 10
// 506.282 us; speedup vs baseline: 1.2886x; 1.0427x over previous
//
#include <hip/hip_runtime.h>
#include <hip/hip_fp16.h>
#include <cstdint>

#define N_NODES 50000
#define M_PAD   50048
#define E_EDGES 800000
#define ETOT (E_EDGES + N_NODES)
#define G_GRAPHS 512
#define FIN 300
#define K1P 320
#define HC 256
#define NHID 300
#define NOUT 512
#define NBLK 196               // ceil(N_NODES / 256)
#define ROWB 391               // M_PAD / 128
#define QROW 49                // ceil(ROWB / 8) row-blocks per XCD

typedef unsigned short u16;
typedef __attribute__((ext_vector_type(8))) _Float16 f16x8;
typedef __attribute__((ext_vector_type(4))) float f32x4;

__device__ __forceinline__ float leaky(float x){ return x > 0.f ? x : 0.2f * x; }

__global__ void zero_i32(int* __restrict__ p, int n){
    int i = blockIdx.x * blockDim.x + threadIdx.x;
    if (i < n) p[i] = 0;
}

__global__ void hist_kernel(const int* __restrict__ ei, int* __restrict__ counts){
    int i = blockIdx.x * blockDim.x + threadIdx.x;
    if (i >= ETOT) return;
    int d = (i < E_EDGES) ? ei[E_EDGES + i] : (i - E_EDGES);
    atomicAdd(&counts[d], 1);
}

// ---- two-level scan ---------------------------------------------------------

__global__ __launch_bounds__(256) void bsum_kernel(const int* __restrict__ counts,
                                                   int* __restrict__ bsum){
    int b = blockIdx.x, t = threadIdx.x;
    int i = b * 256 + t;
    int v = (i < N_NODES) ? counts[i] : 0;
    #pragma unroll
    for (int o = 32; o >= 1; o >>= 1) v += __shfl_xor(v, o, 64);
    __shared__ int ws[4];
    if ((t & 63) == 0) ws[t >> 6] = v;
    __syncthreads();
    if (t == 0) bsum[b] = ws[0] + ws[1] + ws[2] + ws[3];
}

__global__ __launch_bounds__(256) void bscan_kernel(const int* __restrict__ bsum,
                                                    int* __restrict__ boff,
                                                    int* __restrict__ rs){
    int t = threadIdx.x;
    int v = (t < NBLK) ? bsum[t] : 0;
    __shared__ int sd[256];
    sd[t] = v;
    __syncthreads();
    for (int off = 1; off < 256; off <<= 1){
        int u = (t >= off) ? sd[t - off] : 0;
        __syncthreads();
        sd[t] += u;
        __syncthreads();
    }
    if (t < NBLK) boff[t] = sd[t] - v;     // exclusive
    if (t == 0) rs[N_NODES] = ETOT;
}

__global__ __launch_bounds__(256) void offsets_kernel(const int* __restrict__ counts,
                                                      const int* __restrict__ boff,
                                                      int* __restrict__ rs,
                                                      int* __restrict__ cursor){
    int b = blockIdx.x, t = threadIdx.x;
    int i = b * 256 + t;
    int v = (i < N_NODES) ? counts[i] : 0;
    __shared__ int sd[256];
    sd[t] = v;
    __syncthreads();
    for (int off = 1; off < 256; off <<= 1){
        int u = (t >= off) ? sd[t - off] : 0;
        __syncthreads();
        sd[t] += u;
        __syncthreads();
    }
    if (i < N_NODES){
        int o = boff[b] + sd[t] - v;
        rs[i] = o; cursor[i] = o;
    }
}

__global__ void scatter_kernel(const int* __restrict__ ei, int* __restrict__ cursor,
                               int* __restrict__ csr_src){
    int i = blockIdx.x * blockDim.x + threadIdx.x;
    if (i >= ETOT) return;
    int s, d;
    if (i < E_EDGES){ s = ei[i]; d = ei[E_EDGES + i]; }
    else            { s = d = i - E_EDGES; }
    int pos = atomicAdd(&cursor[d], 1);
    csr_src[pos] = s;
}

// ---- conversion kernels: fp32 -> fp16 ---------------------------------------

__global__ void conv_x_kernel(const float* __restrict__ x, __half* __restrict__ xf){
    int row = blockIdx.x, t = threadIdx.x;          // grid M_PAD, block 320
    float v = 0.f;
    if (row < N_NODES && t < FIN) v = x[(size_t)row * FIN + t];
    xf[(size_t)row * K1P + t] = __float2half(v);
}

__global__ void conv_w_kernel(const float* __restrict__ W, __half* __restrict__ wf,
                              int K, int Kp){
    int col = blockIdx.x, k = threadIdx.x;          // grid 256, block Kp
    float v = (k < K) ? W[(size_t)k * HC + col] : 0.f;
    wf[(size_t)col * Kp + k] = __float2half(v);
}

__global__ void pad_h_kernel(__half* __restrict__ hf){
    int row = N_NODES + blockIdx.x;                 // grid 48, block 256
    int t = threadIdx.x;
    hf[(size_t)row * HC + t] = __float2half(0.f);
}

// ---- fp16 MFMA GEMM: Cf[M,256] = A @ W (fp32 accumulate) --------------------
// 1D grid with XCD-affinity swizzle: the 4 col-blocks of one row-block are
// adjacent in issue order on the same XCD -> A-tile shared via private L2.
__global__ __launch_bounds__(256) void gemm_fp16(const __half* __restrict__ A,
                                                 const __half* __restrict__ Bt,
                                                 __half* __restrict__ Cf,
                                                 int Kp, int Mvalid){
    const int bid = blockIdx.x;
    const int xcd = bid & 7, idx = bid >> 3;
    const int cx  = idx & 3, cyl = idx >> 2;
    const int y   = xcd * QROW + cyl;
    if (y >= ROWB || cyl >= QROW) return;
    const int col0 = cx * 64;
    const int row0 = y * 128;

    __shared__ u16 smem[12288];                     // 24 KB
    const int t    = threadIdx.x;
    const int lane = t & 63;
    const int w    = t >> 6, wr = w >> 1, wc = w & 1;
    const int fr   = lane & 15, fq = lane >> 4;

    const int rA0 = t >> 2, sA0 = t & 3;            // A rows 0..63
    const int rA1 = rA0 + 64;                       // A rows 64..127
    const int rB  = t >> 2, sB = t & 3;             // B rows 0..63

    auto aoff = [](int db, int row, int slot)->int{
        return db * 4096 + row * 32 + ((slot ^ ((row >> 1) & 3)) * 8);
    };
    auto boff = [](int db, int row, int slot)->int{
        return 8192 + db * 2048 + row * 32 + ((slot ^ ((row >> 1) & 3)) * 8);
    };

    f32x4 acc[4][2];
    #pragma unroll
    for (int m = 0; m < 4; ++m)
        #pragma unroll
        for (int n = 0; n < 2; ++n) acc[m][n] = (f32x4){0.f, 0.f, 0.f, 0.f};

    const int nt = Kp >> 5;
    int4 va0, va1, vb;

    auto stage_load = [&](int kt){
        const int k0 = kt * 32;
        va0 = *(const int4*)(A  + (size_t)(row0 + rA0) * Kp + k0 + sA0 * 8);
        va1 = *(const int4*)(A  + (size_t)(row0 + rA1) * Kp + k0 + sA0 * 8);
        vb  = *(const int4*)(Bt + (size_t)(col0 + rB ) * Kp + k0 + sB  * 8);
    };
    auto stage_write = [&](int db){
        *(int4*)&smem[aoff(db, rA0, sA0)] = va0;
        *(int4*)&smem[aoff(db, rA1, sA0)] = va1;
        *(int4*)&smem[boff(db, rB,  sB )] = vb;
    };

    stage_load(0); stage_write(0);
    __syncthreads();

    for (int kt = 0; kt < nt; ++kt){
        const int db = kt & 1;
        if (kt + 1 < nt) stage_load(kt + 1);        // issue early

        f16x8 af[4], bf[2];
        #pragma unroll
        for (int m = 0; m < 4; ++m){
            int row = wr * 64 + m * 16 + fr;
            af[m] = *(const f16x8*)&smem[aoff(db, row, fq)];
        }
        #pragma unroll
        for (int n = 0; n < 2; ++n){
            int col = wc * 32 + n * 16 + fr;
            bf[n] = *(const f16x8*)&smem[boff(db, col, fq)];
        }
        #pragma unroll
        for (int m = 0; m < 4; ++m)
            #pragma unroll
            for (int n = 0; n < 2; ++n)
                acc[m][n] = __builtin_amdgcn_mfma_f32_16x16x32_f16(af[m], bf[n], acc[m][n], 0, 0, 0);

        if (kt + 1 < nt) stage_write(db ^ 1);       // write late
        __syncthreads();
    }

    // C/D layout: col = lane&15, row = (lane>>4)*4 + reg
    #pragma unroll
    for (int m = 0; m < 4; ++m){
        int row = row0 + wr * 64 + m * 16 + fq * 4;
        #pragma unroll
        for (int n = 0; n < 2; ++n){
            int col = col0 + wc * 32 + n * 16 + fr;
            #pragma unroll
            for (int r = 0; r < 4; ++r){
                if (row + r < Mvalid)
                    Cf[(size_t)(row + r) * HC + col] = __float2half(acc[m][n][r]);
            }
        }
    }
}

// per-node attention logits from fp16 htf (lane -> cols 4l..4l+3)
__global__ __launch_bounds__(256) void al_kernel(const __half* __restrict__ htf,
                                                 const float* __restrict__ a_s,
                                                 const float* __restrict__ a_d,
                                                 float* __restrict__ als,
                                                 float* __restrict__ ald){
    int wave = threadIdx.x >> 6, lane = threadIdx.x & 63;
    int n = blockIdx.x * 4 + wave;
    if (n >= N_NODES) return;
    const uint2 u = *(const uint2*)(htf + (size_t)n * HC + 4 * lane);
    float2 f01 = __half22float2(*reinterpret_cast<const __half2*>(&u.x));
    float2 f23 = __half22float2(*reinterpret_cast<const __half2*>(&u.y));
    const float4 as4 = *(const float4*)(a_s + 4 * lane);
    const float4 ad4 = *(const float4*)(a_d + 4 * lane);
    float ps = f01.x * as4.x + f01.y * as4.y + f23.x * as4.z + f23.y * as4.w;
    float pd = f01.x * ad4.x + f01.y * ad4.y + f23.x * ad4.z + f23.y * ad4.w;
    #pragma unroll
    for (int o = 8; o >= 1; o >>= 1){       // reduce within 16-lane head group
        ps += __shfl_xor(ps, o, 64);
        pd += __shfl_xor(pd, o, 64);
    }
    if ((lane & 15) == 0){
        als[n * 4 + (lane >> 4)] = ps;
        ald[n * 4 + (lane >> 4)] = pd;
    }
}

// one wave per destination node: segment softmax + weighted aggregation.
// Output always fp16 (pool + next-layer GEMM both consume fp16).
__global__ __launch_bounds__(256) void aggregate_kernel(const __half* __restrict__ htf,
                                                        const float* __restrict__ als,
                                                        const float* __restrict__ ald,
                                                        const int* __restrict__ rs,
                                                        const int* __restrict__ csr,
                                                        const float* __restrict__ bias,
                                                        __half* __restrict__ hf,
                                                        int do_relu){
    int wave = threadIdx.x >> 6, lane = threadIdx.x & 63;
    int n = blockIdx.x * 4 + wave;
    if (n >= N_NODES) return;
    const int s0 = rs[n], s1 = rs[n + 1];
    const int deg = s1 - s0;
    const int hsel = lane >> 4;             // head owning cols 4l..4l+3
    const float4 adv = *(const float4*)(ald + (size_t)n * 4);
    const float ad0 = adv.x, ad1 = adv.y, ad2 = adv.z, ad3 = adv.w;

    float4 acc = {0.f, 0.f, 0.f, 0.f};
    float sm0 = 0.f, sm1 = 0.f, sm2 = 0.f, sm3 = 0.f;

    if (deg <= 64){
        const int i = s0 + lane;
        int s = 0;
        float e0 = -1e30f, e1 = -1e30f, e2 = -1e30f, e3 = -1e30f;
        if (i < s1){
            s = csr[i];
            float4 a = *(const float4*)(als + (size_t)s * 4);
            e0 = leaky(a.x + ad0); e1 = leaky(a.y + ad1);
            e2 = leaky(a.z + ad2); e3 = leaky(a.w + ad3);
        }
        float m0 = e0, m1 = e1, m2 = e2, m3 = e3;
        #pragma unroll
        for (int o = 32; o >= 1; o >>= 1){
            m0 = fmaxf(m0, __shfl_xor(m0, o, 64));
            m1 = fmaxf(m1, __shfl_xor(m1, o, 64));
            m2 = fmaxf(m2, __shfl_xor(m2, o, 64));
            m3 = fmaxf(m3, __shfl_xor(m3, o, 64));
        }
        float ex0 = 0.f, ex1 = 0.f, ex2 = 0.f, ex3 = 0.f;
        if (i < s1){
            ex0 = __expf(e0 - m0); ex1 = __expf(e1 - m1);
            ex2 = __expf(e2 - m2); ex3 = __expf(e3 - m3);
        }
        sm0 = ex0; sm1 = ex1; sm2 = ex2; sm3 = ex3;

        const int dp = (deg + 3) & ~3;
        for (int j = 0; j < dp; j += 4){
            int sj[4]; float aw[4];
            #pragma unroll
            for (int k = 0; k < 4; ++k){
                const int jj = j + k;
                sj[k] = __shfl(s, jj, 64);
                float a0 = __shfl(ex0, jj, 64);
                float a1 = __shfl(ex1, jj, 64);
                float a2 = __shfl(ex2, jj, 64);
                float a3 = __shfl(ex3, jj, 64);
                float x0 = (hsel == 0) ? a0 : a1;
                float x1 = (hsel == 2) ? a2 : a3;
                aw[k] = (hsel < 2) ? x0 : x1;
            }
            uint2 u[4];
            #pragma unroll
            for (int k = 0; k < 4; ++k)
                u[k] = *(const uint2*)(htf + (size_t)sj[k] * HC + 4 * lane);
            #pragma unroll
            for (int k = 0; k < 4; ++k){
                float2 f01 = __half22float2(*reinterpret_cast<const __half2*>(&u[k].x));
                float2 f23 = __half22float2(*reinterpret_cast<const __half2*>(&u[k].y));
                acc.x += aw[k] * f01.x; acc.y += aw[k] * f01.y;
                acc.z += aw[k] * f23.x; acc.w += aw[k] * f23.y;
            }
        }
    } else {
        float m0 = -1e30f, m1 = -1e30f, m2 = -1e30f, m3 = -1e30f;
        for (int i = s0 + lane; i < s1; i += 64){
            int s = csr[i];
            float4 a = *(const float4*)(als + (size_t)s * 4);
            m0 = fmaxf(m0, leaky(a.x + ad0)); m1 = fmaxf(m1, leaky(a.y + ad1));
            m2 = fmaxf(m2, leaky(a.z + ad2)); m3 = fmaxf(m3, leaky(a.w + ad3));
        }
        #pragma unroll
        for (int o = 32; o >= 1; o >>= 1){
            m0 = fmaxf(m0, __shfl_xor(m0, o, 64));
            m1 = fmaxf(m1, __shfl_xor(m1, o, 64));
            m2 = fmaxf(m2, __shfl_xor(m2, o, 64));
            m3 = fmaxf(m3, __shfl_xor(m3, o, 64));
        }
        for (int base = s0; base < s1; base += 64){
            const int i = base + lane;
            int s = 0;
            float ex0 = 0.f, ex1 = 0.f, ex2 = 0.f, ex3 = 0.f;
            if (i < s1){
                s = csr[i];
                float4 a = *(const float4*)(als + (size_t)s * 4);
                ex0 = __expf(leaky(a.x + ad0) - m0);
                ex1 = __expf(leaky(a.y + ad1) - m1);
                ex2 = __expf(leaky(a.z + ad2) - m2);
                ex3 = __expf(leaky(a.w + ad3) - m3);
            }
            sm0 += ex0; sm1 += ex1; sm2 += ex2; sm3 += ex3;
            const int cnt = min(64, s1 - base);
            for (int j = 0; j < cnt; ++j){
                int   sj = __shfl(s,   j, 64);
                float a0 = __shfl(ex0, j, 64);
                float a1 = __shfl(ex1, j, 64);
                float a2 = __shfl(ex2, j, 64);
                float a3 = __shfl(ex3, j, 64);
                float x0 = (hsel == 0) ? a0 : a1;
                float x1 = (hsel == 2) ? a2 : a3;
                float aw = (hsel < 2) ? x0 : x1;
                uint2 u = *(const uint2*)(htf + (size_t)sj * HC + 4 * lane);
                float2 f01 = __half22float2(*reinterpret_cast<const __half2*>(&u.x));
                float2 f23 = __half22float2(*reinterpret_cast<const __half2*>(&u.y));
                acc.x += aw * f01.x; acc.y += aw * f01.y;
                acc.z += aw * f23.x; acc.w += aw * f23.y;
            }
        }
    }

    #pragma unroll
    for (int o = 32; o >= 1; o >>= 1){
        sm0 += __shfl_xor(sm0, o, 64);
        sm1 += __shfl_xor(sm1, o, 64);
        sm2 += __shfl_xor(sm2, o, 64);
        sm3 += __shfl_xor(sm3, o, 64);
    }
    float x0 = (hsel == 0) ? sm0 : sm1;
    float x1 = (hsel == 2) ? sm2 : sm3;
    const float inv = 1.f / (((hsel < 2) ? x0 : x1) + 1e-16f);

    const float4 bv = *(const float4*)(bias + 4 * lane);
    float v0 = acc.x * inv + bv.x;
    float v1 = acc.y * inv + bv.y;
    float v2 = acc.z * inv + bv.z;
    float v3 = acc.w * inv + bv.w;
    if (do_relu){
        v0 = fmaxf(v0, 0.f); v1 = fmaxf(v1, 0.f);
        v2 = fmaxf(v2, 0.f); v3 = fmaxf(v3, 0.f);
    }
    ushort4 p;
    p.x = __half_as_ushort(__float2half(v0));
    p.y = __half_as_ushort(__float2half(v1));
    p.z = __half_as_ushort(__float2half(v2));
    p.w = __half_as_ushort(__float2half(v3));
    *(ushort4*)((u16*)hf + (size_t)n * HC + 4 * lane) = p;
}

__global__ void gstart_kernel(const int* __restrict__ batch, int* __restrict__ gstart){
    int g = blockIdx.x * blockDim.x + threadIdx.x;
    if (g > G_GRAPHS) return;
    int lo = 0, hi = N_NODES;
    while (lo < hi){
        int mid = (lo + hi) >> 1;
        if (batch[mid] < g) lo = mid + 1; else hi = mid;
    }
    gstart[g] = lo;
}

__global__ __launch_bounds__(256) void pool_kernel(const __half* __restrict__ h,
                                                   const int* __restrict__ gstart,
                                                   float* __restrict__ pooled){
    int g = blockIdx.x, t = threadIdx.x;
    int s0 = gstart[g], s1 = gstart[g + 1];
    float sum = 0.f;
    for (int n = s0; n < s1; ++n) sum += __half2float(h[(size_t)n * HC + t]);
    pooled[g * HC + t] = sum / fmaxf((float)(s1 - s0), 1.f);
}

__global__ void mlp1_kernel(const float* __restrict__ pooled, const float* __restrict__ Wm1,
                            const float* __restrict__ bm1, float* __restrict__ z){
    int g = blockIdx.x, j = threadIdx.x;
    if (j >= NHID) return;
    float acc = bm1[j];
    for (int k = 0; k < HC; ++k) acc += pooled[g * HC + k] * Wm1[(size_t)k * NHID + j];
    z[g * NHID + j] = fmaxf(acc, 0.f);
}

__global__ void mlp2_kernel(const float* __restrict__ z, const float* __restrict__ Wm2,
                            const float* __restrict__ bm2, float* __restrict__ out){
    int g = blockIdx.x, j = threadIdx.x;
    float acc = bm2[j];
    for (int k = 0; k < NHID; ++k) acc += z[g * NHID + k] * Wm2[(size_t)k * NOUT + j];
    out[g * NOUT + j] = acc;
}

extern "C" void kernel_launch(void* const* d_in, const int* in_sizes, int n_in,
                              void* d_out, int out_size, void* d_ws, size_t ws_size,
                              hipStream_t stream){
    const float* x    = (const float*)d_in[0];
    const int*   ei   = (const int*)  d_in[1];
    const int*   batch= (const int*)  d_in[2];
    const float* W1   = (const float*)d_in[3];
    const float* a1s  = (const float*)d_in[4];
    const float* a1d  = (const float*)d_in[5];
    const float* b1   = (const float*)d_in[6];
    const float* W2   = (const float*)d_in[7];
    const float* a2s  = (const float*)d_in[8];
    const float* a2d  = (const float*)d_in[9];
    const float* b2   = (const float*)d_in[10];
    const float* W3   = (const float*)d_in[11];
    const float* a3s  = (const float*)d_in[12];
    const float* a3d  = (const float*)d_in[13];
    const float* b3   = (const float*)d_in[14];
    const float* Wm1  = (const float*)d_in[15];
    const float* bm1  = (const float*)d_in[16];
    const float* Wm2  = (const float*)d_in[17];
    const float* bm2  = (const float*)d_in[18];
    float* out = (float*)d_out;

    char* ws = (char*)d_ws;
    size_t off = 0;
    auto alloc = [&](size_t bytes)->char*{
        char* p = ws + off;
        off = (off + bytes + 255) & ~(size_t)255;
        return p;
    };
    __half* xf    = (__half*)alloc((size_t)M_PAD * K1P * 2);    // 32 MB; reused as layer-3 out
    __half* hf    = (__half*)alloc((size_t)M_PAD * HC * 2);
    __half* htf   = (__half*)alloc((size_t)N_NODES * HC * 2);
    __half* hout  = xf;                                         // layer-3 output (xf dead)
    __half* wt1   = (__half*)alloc((size_t)HC * K1P * 2);
    __half* wt2   = (__half*)alloc((size_t)HC * HC * 2);
    __half* wt3   = (__half*)alloc((size_t)HC * HC * 2);
    float* als    = (float*)alloc((size_t)N_NODES * 4 * 4);
    float* ald    = (float*)alloc((size_t)N_NODES * 4 * 4);
    int*   counts = (int*)  alloc((size_t)N_NODES * 4);
    int*   rs     = (int*)  alloc((size_t)(N_NODES + 1) * 4);
    int*   cursor = (int*)  alloc((size_t)N_NODES * 4);
    int*   csr    = (int*)  alloc((size_t)ETOT * 4);
    int*   bsum   = (int*)  alloc(256 * 4);
    int*   boffs  = (int*)  alloc(256 * 4);
    int*   gstart = (int*)  alloc((size_t)(G_GRAPHS + 1) * 4);
    float* pooled = (float*)alloc((size_t)G_GRAPHS * HC * 4);
    float* zbuf   = (float*)alloc((size_t)G_GRAPHS * NHID * 4);

    conv_x_kernel<<<M_PAD, K1P, 0, stream>>>(x, xf);
    conv_w_kernel<<<HC, K1P, 0, stream>>>(W1, wt1, FIN, K1P);
    conv_w_kernel<<<HC, HC, 0, stream>>>(W2, wt2, HC, HC);
    conv_w_kernel<<<HC, HC, 0, stream>>>(W3, wt3, HC, HC);
    pad_h_kernel<<<M_PAD - N_NODES, HC, 0, stream>>>(hf);

    zero_i32<<<(N_NODES + 255) / 256, 256, 0, stream>>>(counts, N_NODES);
    hist_kernel<<<(ETOT + 255) / 256, 256, 0, stream>>>(ei, counts);
    bsum_kernel<<<NBLK, 256, 0, stream>>>(counts, bsum);
    bscan_kernel<<<1, 256, 0, stream>>>(bsum, boffs, rs);
    offsets_kernel<<<NBLK, 256, 0, stream>>>(counts, boffs, rs, cursor);
    scatter_kernel<<<(ETOT + 255) / 256, 256, 0, stream>>>(ei, cursor, csr);
    gstart_kernel<<<3, 256, 0, stream>>>(batch, gstart);

    const int GG = 8 * QROW * 4;           // 1568 blocks, XCD-swizzled

    // layer 1
    gemm_fp16<<<GG, 256, 0, stream>>>(xf, wt1, htf, K1P, N_NODES);
    al_kernel<<<(N_NODES + 3) / 4, 256, 0, stream>>>(htf, a1s, a1d, als, ald);
    aggregate_kernel<<<(N_NODES + 3) / 4, 256, 0, stream>>>(htf, als, ald, rs, csr,
                                                            b1, hf, 1);
    // layer 2
    gemm_fp16<<<GG, 256, 0, stream>>>(hf, wt2, htf, HC, N_NODES);
    al_kernel<<<(N_NODES + 3) / 4, 256, 0, stream>>>(htf, a2s, a2d, als, ald);
    aggregate_kernel<<<(N_NODES + 3) / 4, 256, 0, stream>>>(htf, als, ald, rs, csr,
                                                            b2, hf, 1);
    // layer 3 (output into hout = xf, dead after layer-1 GEMM)
    gemm_fp16<<<GG, 256, 0, stream>>>(hf, wt3, htf, HC, N_NODES);
    al_kernel<<<(N_NODES + 3) / 4, 256, 0, stream>>>(htf, a3s, a3d, als, ald);
    aggregate_kernel<<<(N_NODES + 3) / 4, 256, 0, stream>>>(htf, als, ald, rs, csr,
                                                            b3, hout, 0);

    pool_kernel<<<G_GRAPHS, 256, 0, stream>>>(hout, gstart, pooled);
    mlp1_kernel<<<G_GRAPHS, 320, 0, stream>>>(pooled, Wm1, bm1, zbuf);
    mlp2_kernel<<<G_GRAPHS, 512, 0, stream>>>(zbuf, Wm2, bm2, out);
}